// Round 14
// baseline (498.653 us; speedup 1.0000x reference)
//
#include <hip/hip_runtime.h>
#include <hip/hip_bf16.h>

#define B_ 4
#define S_ 2048
#define HID_ 1024
#define NH_ 16
#define HD_ 64
#define M_ (B_*S_)   // 8192

typedef __attribute__((ext_vector_type(8))) short short8;
typedef __attribute__((ext_vector_type(4))) float f32x4;
typedef __attribute__((ext_vector_type(16))) float f32x16;
typedef __attribute__((ext_vector_type(4))) short short4v;
typedef __attribute__((ext_vector_type(2))) int int2v;
typedef __attribute__((ext_vector_type(4))) int int4v;

static __device__ __forceinline__ short bf16_of(float f){
    union { __hip_bfloat16 h; short s; } u;
    u.h = __float2bfloat16(f);
    return u.s;
}

static __device__ __forceinline__ float bf2f(short s){
    return __int_as_float(((int)(unsigned short)s) << 16);
}

static __device__ __forceinline__ int cvtpk_bf16(float lo, float hi){
    int r;
    asm("v_cvt_pk_bf16_f32 %0, %1, %2" : "=v"(r) : "v"(lo), "v"(hi));
    return r;
}

// partner value across the lane<32 / lane>=32 halves
static __device__ __forceinline__ float half_other(float v, bool lo){
    int2v r = __builtin_amdgcn_permlane32_swap(__float_as_int(v), __float_as_int(v), false, false);
    return __int_as_float(lo ? r.y : r.x);
}

// async global->LDS, 16B per lane; LDS dest must be wave-uniform base (HW adds lane*16)
static __device__ __forceinline__ void gload16(const short* g, short* l){
    __builtin_amdgcn_global_load_lds(
        (const __attribute__((address_space(1))) void*)(g),
        (__attribute__((address_space(3))) void*)(l),
        16, 0, 0);
}

// ---------------- cast hidden f32 -> bf16 ----------------
__global__ __launch_bounds__(256) void cast_x_kernel(const float* __restrict__ x,
                                                     short* __restrict__ xb, int n4){
    int i = blockIdx.x*blockDim.x + threadIdx.x;
    if (i >= n4) return;
    float4 f = reinterpret_cast<const float4*>(x)[i];
    short4v o;
    o.x = bf16_of(f.x); o.y = bf16_of(f.y); o.z = bf16_of(f.z); o.w = bf16_of(f.w);
    reinterpret_cast<short4v*>(xb)[i] = o;
}

// ------------- cast + transpose weight: Wt[n][k] = W[k][n], bf16 -------------
__global__ __launch_bounds__(256) void castT_w_kernel(const float* __restrict__ W,
                                                      short* __restrict__ Wt){
    __shared__ float tl[64][65];
    int k0 = blockIdx.x*64, n0 = blockIdx.y*64;
    int t = threadIdx.x;
    int r = t>>2, cg = (t&3)*16;
    #pragma unroll
    for (int j=0;j<4;j++){
        float4 f = *reinterpret_cast<const float4*>(&W[(k0+r)*HID_ + n0 + cg + j*4]);
        tl[r][cg+j*4+0]=f.x; tl[r][cg+j*4+1]=f.y; tl[r][cg+j*4+2]=f.z; tl[r][cg+j*4+3]=f.w;
    }
    __syncthreads();
    short8 o0, o1;
    #pragma unroll
    for (int j=0;j<8;j++) o0[j] = bf16_of(tl[cg+j][r]);
    #pragma unroll
    for (int j=0;j<8;j++) o1[j] = bf16_of(tl[cg+8+j][r]);
    *reinterpret_cast<short8*>(&Wt[(n0+r)*HID_ + k0 + cg])     = o0;
    *reinterpret_cast<short8*>(&Wt[(n0+r)*HID_ + k0 + cg + 8]) = o1;
}

// ------------- rowidx: per-(b,q) bias-row index (0 = shared amask-only row) -------------
__global__ void idx_kernel(const float* __restrict__ mm_, int* __restrict__ rowidx){
    int b = blockIdx.x;
    int lane = threadIdx.x;  // 64 threads
    const float* m = mm_ + b*S_;
    uint64_t lmask = (lane==0) ? 0ull : (~0ull >> (64-lane));
    int base = 1;
    for (int c=0;c<S_;c+=64){
        bool act = m[c+lane] != 0.f;
        uint64_t bal = __ballot(act);
        int r = __popcll(bal & lmask);
        rowidx[b*S_ + c + lane] = act ? (base + r) : 0;
        base += __popcll(bal);
    }
}

// ------------- deduped bias rows (log2e units, bf16) -------------
__global__ __launch_bounds__(256) void relb2_kernel(const float* __restrict__ rel,
        const float* __restrict__ mm_, const float* __restrict__ am_,
        const int* __restrict__ rowidx, short* __restrict__ relb){
    const float C = 0.1f * 1.44269504f;
    const float L = -10000.f * 1.44269504f;
    const int q = blockIdx.x;
    const int c0 = threadIdx.x * 8;
    float4 r0 = *reinterpret_cast<const float4*>(rel + (size_t)q*2048 + c0);
    float4 r1 = *reinterpret_cast<const float4*>(rel + (size_t)q*2048 + c0 + 4);
    #pragma unroll
    for (int b=0;b<B_;b++){
        float4 a0v = *reinterpret_cast<const float4*>(am_ + b*S_ + c0);
        float4 a1v = *reinterpret_cast<const float4*>(am_ + b*S_ + c0 + 4);
        float amt0 = (1.f-a0v.x)*L, amt1 = (1.f-a0v.y)*L;
        float amt2 = (1.f-a0v.z)*L, amt3 = (1.f-a0v.w)*L;
        float amt4 = (1.f-a1v.x)*L, amt5 = (1.f-a1v.y)*L;
        float amt6 = (1.f-a1v.z)*L, amt7 = (1.f-a1v.w)*L;
        if (q == 0){
            short8 o;
            o[0]=bf16_of(amt0); o[1]=bf16_of(amt1); o[2]=bf16_of(amt2); o[3]=bf16_of(amt3);
            o[4]=bf16_of(amt4); o[5]=bf16_of(amt5); o[6]=bf16_of(amt6); o[7]=bf16_of(amt7);
            *reinterpret_cast<short8*>(relb + ((size_t)b<<22) + c0) = o;
        }
        float mq = mm_[b*S_ + q];
        if (mq != 0.f){
            int ridx = rowidx[b*S_ + q];
            ridx = ridx > 2039 ? 2039 : ridx;
            float mqC = mq * C;
            float4 k0v = *reinterpret_cast<const float4*>(mm_ + b*S_ + c0);
            float4 k1v = *reinterpret_cast<const float4*>(mm_ + b*S_ + c0 + 4);
            short8 o;
            o[0]=bf16_of(fmaf(mqC*k0v.x, r0.x, amt0));
            o[1]=bf16_of(fmaf(mqC*k0v.y, r0.y, amt1));
            o[2]=bf16_of(fmaf(mqC*k0v.z, r0.z, amt2));
            o[3]=bf16_of(fmaf(mqC*k0v.w, r0.w, amt3));
            o[4]=bf16_of(fmaf(mqC*k1v.x, r1.x, amt4));
            o[5]=bf16_of(fmaf(mqC*k1v.y, r1.y, amt5));
            o[6]=bf16_of(fmaf(mqC*k1v.z, r1.z, amt6));
            o[7]=bf16_of(fmaf(mqC*k1v.w, r1.w, amt7));
            *reinterpret_cast<short8*>(relb + ((size_t)b<<22) + (size_t)ridx*2048 + c0) = o;
        }
    }
}

// ------------- GEMM (m97 pattern): global_load_lds staging, linear LDS -------------
// OMODE 0: fused QKV (Wt is [3072][1024]); bf16 headed [b,h,s,d]; Q pre-scaled by CQ
// OMODE 1: single (Wt [1024][1024]); bf16 flat [m][n] to o0
template<int OMODE>
__global__ __launch_bounds__(256) void gemm_bt(const short* __restrict__ A,
        const short* __restrict__ Wt, const float* __restrict__ bb0,
        const float* __restrict__ bb1, const float* __restrict__ bb2,
        short* __restrict__ o0, short* __restrict__ o1, short* __restrict__ o2){
    __shared__ short As[128*32];   // 8 KB, linear [128][32]
    __shared__ short Bs[128*32];
    int tid = threadIdx.x;
    int lane = tid & 63, wid = tid >> 6;
    int wm = wid >> 1, wn = wid & 1;
    int lr = lane & 15, lg = lane >> 4;
    // XCD-aware swizzle: per XCD, A-panel (8 m-tiles) stays L2-resident
    const int id = blockIdx.x;
    const int s_ = id >> 3;
    const int ntile = s_ >> 3;
    const int mtile = (id & 7)*8 + (s_ & 7);
    const int m0 = mtile*128, n0 = ntile*128;

    const int ch = wid*128 + lane;
    const int sr = ch >> 2, sc = (ch & 3)*8;
    const short* Ab = A  + (size_t)(m0+sr)*1024 + sc;
    const short* Bb = Wt + (size_t)(n0+sr)*1024 + sc;
    short* lA0 = As + wid*1024;        // wave-uniform LDS bases
    short* lA1 = As + wid*1024 + 512;
    short* lB0 = Bs + wid*1024;
    short* lB1 = Bs + wid*1024 + 512;

    f32x4 acc[4][4] = {};
    for (int kk = 0; kk < 1024; kk += 32){
        gload16(Ab + kk,            lA0);
        gload16(Ab + kk + 16*1024,  lA1);
        gload16(Bb + kk,            lB0);
        gload16(Bb + kk + 16*1024,  lB1);
        __syncthreads();
        short8 af[4], bfr[4];
        #pragma unroll
        for (int x=0;x<4;x++){
            af[x]  = *reinterpret_cast<const short8*>(&As[(wm*64 + x*16 + lr)*32 + lg*8]);
            bfr[x] = *reinterpret_cast<const short8*>(&Bs[(wn*64 + x*16 + lr)*32 + lg*8]);
        }
        #pragma unroll
        for (int mi=0;mi<4;mi++)
            #pragma unroll
            for (int ni=0;ni<4;ni++)
                acc[mi][ni] = __builtin_amdgcn_mfma_f32_16x16x32_bf16(af[mi], bfr[ni], acc[mi][ni], 0,0,0);
        __syncthreads();
    }
    #pragma unroll
    for (int mi=0;mi<4;mi++){
      #pragma unroll
      for (int ni=0;ni<4;ni++){
        int colg = n0 + wn*64 + ni*16 + lr;
        const float* bp; short* op; int cc; int sel = 0;
        if (OMODE == 0){
            sel = colg >> 10; cc = colg & 1023;
            bp = sel==0 ? bb0 : (sel==1 ? bb1 : bb2);
            op = sel==0 ? o0 : (sel==1 ? o1 : o2);
        } else { bp = bb0; cc = colg; op = o0; }
        float bv = bp[cc];
        #pragma unroll
        for (int r=0;r<4;r++){
            int rowg = m0 + wm*64 + mi*16 + lg*4 + r;
            float v = acc[mi][ni][r] + bv;
            if (OMODE == 0){
                if (sel == 0) v *= 0.18033688f;   // Q pre-scaled by 0.125*log2(e)
                int bidx = rowg >> 11, ss = rowg & 2047;
                int hh = cc >> 6, d = cc & 63;
                op[(((size_t)bidx*NH_ + hh)*S_ + ss)*HD_ + d] = bf16_of(v);
            } else {
                op[(size_t)rowg*1024 + colg] = bf16_of(v);
            }
        }
      }
    }
}

// ------------- transpose V: [b,h,s,d] -> [b,h,d,s] (bf16) -------------
__global__ __launch_bounds__(256) void transpose_v(const short* __restrict__ vb,
                                                   short* __restrict__ vt){
    __shared__ short tl[64*72];
    int bh = blockIdx.z*NH_ + blockIdx.y;
    int s0 = blockIdx.x*64;
    int t = threadIdx.x;
    int c8 = (t&7)*8;
    #pragma unroll
    for (int i=0;i<2;i++){
        int row = (t>>3) + i*32;
        *reinterpret_cast<short8*>(&tl[row*72 + c8]) =
            *reinterpret_cast<const short8*>(&vb[((size_t)bh*S_ + s0 + row)*HD_ + c8]);
    }
    __syncthreads();
    #pragma unroll
    for (int i=0;i<2;i++){
        int d = (t>>3) + i*32;
        short8 o;
        #pragma unroll
        for (int j=0;j<8;j++) o[j] = tl[(c8+j)*72 + d];
        *reinterpret_cast<short8*>(&vt[((size_t)bh*HD_ + d)*S_ + s0 + c8]) = o;
    }
}

// ------------- fused attention v10: attn7 structure, no-max softmax, unroll 1 -------------
// Scores bounded (|QK/8*log2e| ~ O(5)); masked cols -> exp2(-14400)=0 -> no max needed.
// #pragma unroll 1 prevents the cross-iteration unroll/pipelining that spilled attn9.
__global__ __launch_bounds__(256, 4) void attn10_kernel(
    const short* __restrict__ qb, const short* __restrict__ kbuf,
    const short* __restrict__ vtg, const short* __restrict__ relb,
    const int* __restrict__ rowidx, short* __restrict__ ctxg)
{
    __shared__ alignas(16) char smem[32768];   // K dbuf [2][64][64], V dbuf [2][64][64]
    const int t = threadIdx.x;
    const int lane = t & 63, wid = t >> 6;
    const int hi = lane >> 5, lr = lane & 31, lr7 = lr & 7;
    const bool lo = (hi == 0);
    // XCD-aware swizzle: 16 q-tiles x 8 heads (same batch) per XCD
    const int id = blockIdx.x;
    const int g = (id & 7)*128 + (id >> 3);
    const int qt = g & 15, bh = g >> 4;
    const int h = bh & 15, b = bh >> 4;
    const int q = qt*128 + wid*32 + lr;

    // Q fragments (B-operand), already scaled by 0.125*log2(e)
    short8 qf[4];
    #pragma unroll
    for (int mm=0;mm<4;mm++)
        qf[mm] = *reinterpret_cast<const short8*>(&qb[((size_t)bh*S_ + q)*HD_ + mm*16 + hi*8]);

    int ridx = rowidx[b*S_ + q];
    ridx = ridx > 2039 ? 2039 : ridx;
    // pre-offset by 4*hi: all fragment extracts become static
    const short* relrow = relb + ((size_t)b<<22) + (size_t)ridx*2048 + 4*hi;

    float l_run = 0.f;
    f32x16 oa0 = {}, oa1 = {};

    const short* kg_base = kbuf + (size_t)bh*S_*HD_;
    const short* vg_base = vtg  + (size_t)bh*HD_*S_;

    // staging geometry: per wave, lane l loads chunk c = base + (l ^ ((l>>3)&7));
    // LDS dest linear (base + lane*16 by HW) -> content matches XOR-swizzled layout.
    const int pl = lane ^ ((lane>>3)&7);
    const int c0 = wid*64 + pl;
    const int c1 = c0 + 256;
    const size_t ks0 = (size_t)c0*8, ks1 = (size_t)c1*8;
    const size_t vs0 = (size_t)(c0>>3)*S_ + (size_t)(c0&7)*8;
    const size_t vs1 = (size_t)(c1>>3)*S_ + (size_t)(c1&7)*8;
    const int lb0 = wid*1024;
    const int lb1 = wid*1024 + 4096;

    // prologue: stage K/V tile 0 into buffer 0; load bias tile 0 into rbc
    gload16(kg_base + ks0, (short*)(smem + lb0));
    gload16(kg_base + ks1, (short*)(smem + lb1));
    gload16(vg_base + vs0, (short*)(smem + 16384 + lb0));
    gload16(vg_base + vs1, (short*)(smem + 16384 + lb1));
    short4v rbc[8], rbn[8];
    #pragma unroll
    for (int j=0;j<8;j++) rbc[j] = *reinterpret_cast<const short4v*>(relrow + j*8);
    __syncthreads();

    int cur = 0;
    const int NT = S_/64;
    #pragma unroll 1
    for (int tt = 0; tt < NT; ++tt){
        const int kb0 = tt*64;
        // issue next-tile staging first (completion enforced by barrier at tile end)
        if (tt < NT-1){
            const short* kg = kg_base + (size_t)(kb0+64)*HD_;
            const short* vg = vg_base + (kb0+64);
            char* kd = smem + (cur^1)*8192;
            char* vd = smem + 16384 + (cur^1)*8192;
            gload16(kg + ks0, (short*)(kd + lb0));
            gload16(kg + ks1, (short*)(kd + lb1));
            gload16(vg + vs0, (short*)(vd + lb0));
            gload16(vg + vs1, (short*)(vd + lb1));
            const short* rr = relrow + kb0 + 64;
            #pragma unroll
            for (int j=0;j<8;j++) rbn[j] = *reinterpret_cast<const short4v*>(rr + j*8);
        }
        char* kb_lds = smem + cur*8192;
        char* vb_lds = smem + 16384 + cur*8192;

        // ---- C-init: bias goes in as the QK accumulator ----
        f32x16 p0, p1;
        #pragma unroll
        for (int g2=0; g2<4; g2++){
            #pragma unroll
            for (int i=0;i<4;i++){
                p0[4*g2+i] = bf2f(rbc[g2][i]);
                p1[4*g2+i] = bf2f(rbc[4+g2][i]);
            }
        }

        // ---- QK^T (swapped), scores come out fully scaled+biased (log2 units) ----
        __builtin_amdgcn_s_setprio(1);
        #pragma unroll
        for (int mm=0;mm<4;mm++){
            int swz = ((2*mm+hi) ^ lr7) << 4;
            short8 kf0 = *(const short8*)(kb_lds + lr*128 + swz);
            short8 kf1 = *(const short8*)(kb_lds + (32+lr)*128 + swz);
            p0 = __builtin_amdgcn_mfma_f32_32x32x16_bf16(kf0, qf[mm], p0, 0,0,0);
            p1 = __builtin_amdgcn_mfma_f32_32x32x16_bf16(kf1, qf[mm], p1, 0,0,0);
        }
        __builtin_amdgcn_s_setprio(0);

        // ---- no-max softmax: p = exp2(score) directly ----
        #pragma unroll
        for (int r=0;r<16;r++) p0[r] = exp2f(p0[r]);
        #pragma unroll
        for (int r=0;r<16;r++) p1[r] = exp2f(p1[r]);

        float s00 = (p0[0]+p0[1])+(p0[2]+p0[3]);
        float s01 = (p0[4]+p0[5])+(p0[6]+p0[7]);
        float s02 = (p0[8]+p0[9])+(p0[10]+p0[11]);
        float s03 = (p0[12]+p0[13])+(p0[14]+p0[15]);
        float s10 = (p1[0]+p1[1])+(p1[2]+p1[3]);
        float s11 = (p1[4]+p1[5])+(p1[6]+p1[7]);
        float s12 = (p1[8]+p1[9])+(p1[10]+p1[11]);
        float s13 = (p1[12]+p1[13])+(p1[14]+p1[15]);
        float rs = ((s00+s01)+(s02+s03)) + ((s10+s11)+(s12+s13));
        rs += half_other(rs, lo);
        l_run += rs;

        // ---- P -> bf16 B-fragments via cvt_pk + permlane32_swap ----
        short8 pf[4];
        #pragma unroll
        for (int kb=0;kb<4;kb++){
            const f32x16& P = (kb<2) ? p0 : p1;
            const int r0 = 8*(kb&1);
            int X0 = cvtpk_bf16(P[r0+0], P[r0+1]);
            int Y0 = cvtpk_bf16(P[r0+2], P[r0+3]);
            int X1 = cvtpk_bf16(P[r0+4], P[r0+5]);
            int Y1 = cvtpk_bf16(P[r0+6], P[r0+7]);
            int2v w02 = __builtin_amdgcn_permlane32_swap(X0, X1, false, false);
            int2v w13 = __builtin_amdgcn_permlane32_swap(Y0, Y1, false, false);
            pf[kb] = __builtin_bit_cast(short8, (int4v){w02.x, w13.x, w02.y, w13.y});
        }

        // ---- PV (swapped) ----
        __builtin_amdgcn_s_setprio(1);
        #pragma unroll
        for (int kb=0;kb<4;kb++){
            int swz = ((2*kb+hi) ^ lr7) << 4;
            short8 vf0 = *(const short8*)(vb_lds + lr*128 + swz);
            short8 vf1 = *(const short8*)(vb_lds + (32+lr)*128 + swz);
            oa0 = __builtin_amdgcn_mfma_f32_32x32x16_bf16(vf0, pf[kb], oa0, 0,0,0);
            oa1 = __builtin_amdgcn_mfma_f32_32x32x16_bf16(vf1, pf[kb], oa1, 0,0,0);
        }
        __builtin_amdgcn_s_setprio(0);

        // ---- rotate bias regs; barrier completes the in-flight LDS stage ----
        if (tt < NT-1){
            #pragma unroll
            for (int j=0;j<8;j++) rbc[j] = rbn[j];
        }
        __syncthreads();
        cur ^= 1;
    }

    // ---- epilogue: O/l -> bf16, LDS transpose stage, coalesced store ----
    char* ost = smem + wid*4096;
    float invl = 1.f / l_run;
    #pragma unroll
    for (int db=0; db<2; db++){
        const f32x16& O = (db==0) ? oa0 : oa1;
        #pragma unroll
        for (int g2=0; g2<4; g2++){
            int w0 = cvtpk_bf16(O[4*g2+0]*invl, O[4*g2+1]*invl);
            int w1 = cvtpk_bf16(O[4*g2+2]*invl, O[4*g2+3]*invl);
            int by = lr*128 + (((4*db+g2) ^ lr7)<<4) + hi*8;
            *reinterpret_cast<int2v*>(ost + by) = (int2v){w0, w1};
        }
    }
    __syncthreads();
    const size_t obase = ((size_t)b*S_ + qt*128 + wid*32)*HID_ + h*HD_;
    #pragma unroll
    for (int i=0;i<4;i++){
        int row = i*8 + (lane>>3);
        int c = lane&7;
        short8 v = *(const short8*)(ost + row*128 + ((c ^ (row&7))<<4));
        *reinterpret_cast<short8*>(&ctxg[obase + (size_t)row*HID_ + c*8]) = v;
    }
}

// ------------- residual + LayerNorm (og now bf16) -------------
__global__ __launch_bounds__(256) void ln_kernel(const short* __restrict__ og,
    const float* __restrict__ hidden, const float* __restrict__ g,
    const float* __restrict__ bb, float* __restrict__ out){
    int row = blockIdx.x;
    int t = threadIdx.x;
    short4v ov = *reinterpret_cast<const short4v*>(&og[(size_t)row*HID_ + t*4]);
    float4 hv = *reinterpret_cast<const float4*>(&hidden[(size_t)row*HID_ + t*4]);
    float x0 = bf2f(ov.x) + hv.x, x1 = bf2f(ov.y) + hv.y;
    float x2 = bf2f(ov.z) + hv.z, x3 = bf2f(ov.w) + hv.w;
    float s = x0+x1+x2+x3;
    float qq = x0*x0+x1*x1+x2*x2+x3*x3;
    #pragma unroll
    for (int off=1;off<64;off<<=1){ s += __shfl_xor(s,off); qq += __shfl_xor(qq,off); }
    __shared__ float rs[4], rq[4];
    int lane = t&63, wid = t>>6;
    if (lane==0){ rs[wid]=s; rq[wid]=qq; }
    __syncthreads();
    s = rs[0]+rs[1]+rs[2]+rs[3];
    qq = rq[0]+rq[1]+rq[2]+rq[3];
    float mu  = s * (1.f/1024.f);
    float var = qq * (1.f/1024.f) - mu*mu;
    float inv = rsqrtf(var + 1e-12f);
    float4 gv = *reinterpret_cast<const float4*>(&g[t*4]);
    float4 bv = *reinterpret_cast<const float4*>(&bb[t*4]);
    float4 y;
    y.x = (x0-mu)*inv*gv.x + bv.x;
    y.y = (x1-mu)*inv*gv.y + bv.y;
    y.z = (x2-mu)*inv*gv.z + bv.z;
    y.w = (x3-mu)*inv*gv.w + bv.w;
    *reinterpret_cast<float4*>(&out[(size_t)row*HID_ + t*4]) = y;
}

extern "C" void kernel_launch(void* const* d_in, const int* in_sizes, int n_in,
                              void* d_out, int out_size, void* d_ws, size_t ws_size,
                              hipStream_t stream){
    const float* hidden = (const float*)d_in[0];
    const float* amask  = (const float*)d_in[1];
    const float* mmask  = (const float*)d_in[2];
    const float* Wq = (const float*)d_in[3];
    const float* bq = (const float*)d_in[4];
    const float* Wk = (const float*)d_in[5];
    const float* bk = (const float*)d_in[6];
    const float* Wv = (const float*)d_in[7];
    const float* bv = (const float*)d_in[8];
    const float* rel = (const float*)d_in[9];
    const float* Wd = (const float*)d_in[10];
    const float* bd = (const float*)d_in[11];
    const float* lng = (const float*)d_in[12];
    const float* lnb = (const float*)d_in[13];
    float* out = (float*)d_out;

    char* ws = (char*)d_ws;
    // layout (104 MB total):
    short* xb   = (short*)(ws);                      // 0-16MB   bf16 hidden (dead after QKV gemm)
    short* vtb  = (short*)(ws);                      // 0-16MB   v [b,h,d,s] (after xb dies)
    short* wt   = (short*)(ws + (16u<<20));          // 16-24MB  4x bf16 W^T (QKV fused + Wd)
    short* qb   = (short*)(ws + (24u<<20));          // 24-40MB  q [b,h,s,d] (pre-scaled by CQ)
    short* kb2  = (short*)(ws + (40u<<20));          // 40-56MB  k [b,h,s,d]
    short* vb   = (short*)(ws + (56u<<20));          // 56-72MB  v [b,h,s,d] (dead after transpose_v)
    short* ctx  = (short*)(ws + (56u<<20));          // 56-72MB  ctx (after vb dies)
    short* relb = (short*)(ws + (72u<<20));          // 72-104MB deduped bias rows [4][<=2040][2048] bf16
    short* og   = (short*)(ws + (24u<<20));          // 24-40MB  bf16, aliases qb (dead after attn)
    int* rowidx = (int*)(ws + (104u<<20) - (32u<<10)); // 32KB, tail of relb region (rows >2039 unused)

    cast_x_kernel<<<8192, 256, 0, stream>>>(hidden, xb, M_*HID_/4);
    dim3 gw(16,16);
    castT_w_kernel<<<gw, 256, 0, stream>>>(Wq, wt + 0*(1u<<20));
    castT_w_kernel<<<gw, 256, 0, stream>>>(Wk, wt + 1*(1u<<20));
    castT_w_kernel<<<gw, 256, 0, stream>>>(Wv, wt + 2*(1u<<20));
    castT_w_kernel<<<gw, 256, 0, stream>>>(Wd, wt + 3*(1u<<20));
    idx_kernel<<<4, 64, 0, stream>>>(mmask, rowidx);
    relb2_kernel<<<2048, 256, 0, stream>>>(rel, mmask, amask, rowidx, relb);
    // fused QKV gemm: N=3072 over concatenated W^T (last use of xb)
    gemm_bt<0><<<1536, 256, 0, stream>>>(xb, wt, bq, bk, bv, qb, kb2, vb);
    // xb dead -> vtb takes its region; vb dead after this
    transpose_v<<<dim3(32,NH_,B_), 256, 0, stream>>>(vb, vtb);
    attn10_kernel<<<1024, 256, 0, stream>>>(qb, kb2, vtb, relb, rowidx, ctx);
    gemm_bt<1><<<512, 256, 0, stream>>>(ctx, wt + 3*(1u<<20), bd, nullptr, nullptr,
                                        og, nullptr, nullptr);
    ln_kernel<<<8192, 256, 0, stream>>>(og, hidden, lng, lnb, out);
}

// Round 15
// 278.983 us; speedup vs baseline: 1.7874x; 1.7874x over previous
//
#include <hip/hip_runtime.h>
#include <hip/hip_bf16.h>

#define B_ 4
#define S_ 2048
#define HID_ 1024
#define NH_ 16
#define HD_ 64
#define M_ (B_*S_)   // 8192

typedef __attribute__((ext_vector_type(8))) short short8;
typedef __attribute__((ext_vector_type(4))) float f32x4;
typedef __attribute__((ext_vector_type(16))) float f32x16;
typedef __attribute__((ext_vector_type(4))) short short4v;
typedef __attribute__((ext_vector_type(2))) int int2v;
typedef __attribute__((ext_vector_type(4))) int int4v;

static __device__ __forceinline__ short bf16_of(float f){
    union { __hip_bfloat16 h; short s; } u;
    u.h = __float2bfloat16(f);
    return u.s;
}

static __device__ __forceinline__ float bf2f(short s){
    return __int_as_float(((int)(unsigned short)s) << 16);
}

static __device__ __forceinline__ int cvtpk_bf16(float lo, float hi){
    int r;
    asm("v_cvt_pk_bf16_f32 %0, %1, %2" : "=v"(r) : "v"(lo), "v"(hi));
    return r;
}

// partner value across the lane<32 / lane>=32 halves
static __device__ __forceinline__ float half_other(float v, bool lo){
    int2v r = __builtin_amdgcn_permlane32_swap(__float_as_int(v), __float_as_int(v), false, false);
    return __int_as_float(lo ? r.y : r.x);
}

// async global->LDS, 16B per lane; LDS dest must be wave-uniform base (HW adds lane*16)
static __device__ __forceinline__ void gload16(const short* g, short* l){
    __builtin_amdgcn_global_load_lds(
        (const __attribute__((address_space(1))) void*)(g),
        (__attribute__((address_space(3))) void*)(l),
        16, 0, 0);
}

// ---------------- cast hidden f32 -> bf16 ----------------
__global__ __launch_bounds__(256) void cast_x_kernel(const float* __restrict__ x,
                                                     short* __restrict__ xb, int n4){
    int i = blockIdx.x*blockDim.x + threadIdx.x;
    if (i >= n4) return;
    float4 f = reinterpret_cast<const float4*>(x)[i];
    short4v o;
    o.x = bf16_of(f.x); o.y = bf16_of(f.y); o.z = bf16_of(f.z); o.w = bf16_of(f.w);
    reinterpret_cast<short4v*>(xb)[i] = o;
}

// ------------- cast + transpose weight: Wt[n][k] = W[k][n], bf16 -------------
__global__ __launch_bounds__(256) void castT_w_kernel(const float* __restrict__ W,
                                                      short* __restrict__ Wt){
    __shared__ float tl[64][65];
    int k0 = blockIdx.x*64, n0 = blockIdx.y*64;
    int t = threadIdx.x;
    int r = t>>2, cg = (t&3)*16;
    #pragma unroll
    for (int j=0;j<4;j++){
        float4 f = *reinterpret_cast<const float4*>(&W[(k0+r)*HID_ + n0 + cg + j*4]);
        tl[r][cg+j*4+0]=f.x; tl[r][cg+j*4+1]=f.y; tl[r][cg+j*4+2]=f.z; tl[r][cg+j*4+3]=f.w;
    }
    __syncthreads();
    short8 o0, o1;
    #pragma unroll
    for (int j=0;j<8;j++) o0[j] = bf16_of(tl[cg+j][r]);
    #pragma unroll
    for (int j=0;j<8;j++) o1[j] = bf16_of(tl[cg+8+j][r]);
    *reinterpret_cast<short8*>(&Wt[(n0+r)*HID_ + k0 + cg])     = o0;
    *reinterpret_cast<short8*>(&Wt[(n0+r)*HID_ + k0 + cg + 8]) = o1;
}

// ------------- rowidx: per-(b,q) bias-row index (0 = shared amask-only row) -------------
__global__ void idx_kernel(const float* __restrict__ mm_, int* __restrict__ rowidx){
    int b = blockIdx.x;
    int lane = threadIdx.x;  // 64 threads
    const float* m = mm_ + b*S_;
    uint64_t lmask = (lane==0) ? 0ull : (~0ull >> (64-lane));
    int base = 1;
    for (int c=0;c<S_;c+=64){
        bool act = m[c+lane] != 0.f;
        uint64_t bal = __ballot(act);
        int r = __popcll(bal & lmask);
        rowidx[b*S_ + c + lane] = act ? (base + r) : 0;
        base += __popcll(bal);
    }
}

// ------------- deduped bias rows (log2e units, bf16) -------------
__global__ __launch_bounds__(256) void relb2_kernel(const float* __restrict__ rel,
        const float* __restrict__ mm_, const float* __restrict__ am_,
        const int* __restrict__ rowidx, short* __restrict__ relb){
    const float C = 0.1f * 1.44269504f;
    const float L = -10000.f * 1.44269504f;
    const int q = blockIdx.x;
    const int c0 = threadIdx.x * 8;
    float4 r0 = *reinterpret_cast<const float4*>(rel + (size_t)q*2048 + c0);
    float4 r1 = *reinterpret_cast<const float4*>(rel + (size_t)q*2048 + c0 + 4);
    #pragma unroll
    for (int b=0;b<B_;b++){
        float4 a0v = *reinterpret_cast<const float4*>(am_ + b*S_ + c0);
        float4 a1v = *reinterpret_cast<const float4*>(am_ + b*S_ + c0 + 4);
        float amt0 = (1.f-a0v.x)*L, amt1 = (1.f-a0v.y)*L;
        float amt2 = (1.f-a0v.z)*L, amt3 = (1.f-a0v.w)*L;
        float amt4 = (1.f-a1v.x)*L, amt5 = (1.f-a1v.y)*L;
        float amt6 = (1.f-a1v.z)*L, amt7 = (1.f-a1v.w)*L;
        if (q == 0){
            short8 o;
            o[0]=bf16_of(amt0); o[1]=bf16_of(amt1); o[2]=bf16_of(amt2); o[3]=bf16_of(amt3);
            o[4]=bf16_of(amt4); o[5]=bf16_of(amt5); o[6]=bf16_of(amt6); o[7]=bf16_of(amt7);
            *reinterpret_cast<short8*>(relb + ((size_t)b<<22) + c0) = o;
        }
        float mq = mm_[b*S_ + q];
        if (mq != 0.f){
            int ridx = rowidx[b*S_ + q];
            ridx = ridx > 2039 ? 2039 : ridx;
            float mqC = mq * C;
            float4 k0v = *reinterpret_cast<const float4*>(mm_ + b*S_ + c0);
            float4 k1v = *reinterpret_cast<const float4*>(mm_ + b*S_ + c0 + 4);
            short8 o;
            o[0]=bf16_of(fmaf(mqC*k0v.x, r0.x, amt0));
            o[1]=bf16_of(fmaf(mqC*k0v.y, r0.y, amt1));
            o[2]=bf16_of(fmaf(mqC*k0v.z, r0.z, amt2));
            o[3]=bf16_of(fmaf(mqC*k0v.w, r0.w, amt3));
            o[4]=bf16_of(fmaf(mqC*k1v.x, r1.x, amt4));
            o[5]=bf16_of(fmaf(mqC*k1v.y, r1.y, amt5));
            o[6]=bf16_of(fmaf(mqC*k1v.z, r1.z, amt6));
            o[7]=bf16_of(fmaf(mqC*k1v.w, r1.w, amt7));
            *reinterpret_cast<short8*>(relb + ((size_t)b<<22) + (size_t)ridx*2048 + c0) = o;
        }
    }
}

// ------------- GEMM (m97 pattern): global_load_lds staging, linear LDS -------------
// OMODE 0: fused QKV (Wt is [3072][1024]); bf16 headed [b,h,s,d]; Q pre-scaled by CQ
// OMODE 1: single (Wt [1024][1024]); bf16 flat [m][n] to o0
template<int OMODE>
__global__ __launch_bounds__(256) void gemm_bt(const short* __restrict__ A,
        const short* __restrict__ Wt, const float* __restrict__ bb0,
        const float* __restrict__ bb1, const float* __restrict__ bb2,
        short* __restrict__ o0, short* __restrict__ o1, short* __restrict__ o2){
    __shared__ short As[128*32];   // 8 KB, linear [128][32]
    __shared__ short Bs[128*32];
    int tid = threadIdx.x;
    int lane = tid & 63, wid = tid >> 6;
    int wm = wid >> 1, wn = wid & 1;
    int lr = lane & 15, lg = lane >> 4;
    // XCD-aware swizzle: per XCD, A-panel (8 m-tiles) stays L2-resident
    const int id = blockIdx.x;
    const int s_ = id >> 3;
    const int ntile = s_ >> 3;
    const int mtile = (id & 7)*8 + (s_ & 7);
    const int m0 = mtile*128, n0 = ntile*128;

    const int ch = wid*128 + lane;
    const int sr = ch >> 2, sc = (ch & 3)*8;
    const short* Ab = A  + (size_t)(m0+sr)*1024 + sc;
    const short* Bb = Wt + (size_t)(n0+sr)*1024 + sc;
    short* lA0 = As + wid*1024;        // wave-uniform LDS bases
    short* lA1 = As + wid*1024 + 512;
    short* lB0 = Bs + wid*1024;
    short* lB1 = Bs + wid*1024 + 512;

    f32x4 acc[4][4] = {};
    for (int kk = 0; kk < 1024; kk += 32){
        gload16(Ab + kk,            lA0);
        gload16(Ab + kk + 16*1024,  lA1);
        gload16(Bb + kk,            lB0);
        gload16(Bb + kk + 16*1024,  lB1);
        __syncthreads();
        short8 af[4], bfr[4];
        #pragma unroll
        for (int x=0;x<4;x++){
            af[x]  = *reinterpret_cast<const short8*>(&As[(wm*64 + x*16 + lr)*32 + lg*8]);
            bfr[x] = *reinterpret_cast<const short8*>(&Bs[(wn*64 + x*16 + lr)*32 + lg*8]);
        }
        #pragma unroll
        for (int mi=0;mi<4;mi++)
            #pragma unroll
            for (int ni=0;ni<4;ni++)
                acc[mi][ni] = __builtin_amdgcn_mfma_f32_16x16x32_bf16(af[mi], bfr[ni], acc[mi][ni], 0,0,0);
        __syncthreads();
    }
    #pragma unroll
    for (int mi=0;mi<4;mi++){
      #pragma unroll
      for (int ni=0;ni<4;ni++){
        int colg = n0 + wn*64 + ni*16 + lr;
        const float* bp; short* op; int cc; int sel = 0;
        if (OMODE == 0){
            sel = colg >> 10; cc = colg & 1023;
            bp = sel==0 ? bb0 : (sel==1 ? bb1 : bb2);
            op = sel==0 ? o0 : (sel==1 ? o1 : o2);
        } else { bp = bb0; cc = colg; op = o0; }
        float bv = bp[cc];
        #pragma unroll
        for (int r=0;r<4;r++){
            int rowg = m0 + wm*64 + mi*16 + lg*4 + r;
            float v = acc[mi][ni][r] + bv;
            if (OMODE == 0){
                if (sel == 0) v *= 0.18033688f;   // Q pre-scaled by 0.125*log2(e)
                int bidx = rowg >> 11, ss = rowg & 2047;
                int hh = cc >> 6, d = cc & 63;
                op[(((size_t)bidx*NH_ + hh)*S_ + ss)*HD_ + d] = bf16_of(v);
            } else {
                op[(size_t)rowg*1024 + colg] = bf16_of(v);
            }
        }
      }
    }
}

// ------------- transpose V: [b,h,s,d] -> [b,h,d,s] (bf16) -------------
__global__ __launch_bounds__(256) void transpose_v(const short* __restrict__ vb,
                                                   short* __restrict__ vt){
    __shared__ short tl[64*72];
    int bh = blockIdx.z*NH_ + blockIdx.y;
    int s0 = blockIdx.x*64;
    int t = threadIdx.x;
    int c8 = (t&7)*8;
    #pragma unroll
    for (int i=0;i<2;i++){
        int row = (t>>3) + i*32;
        *reinterpret_cast<short8*>(&tl[row*72 + c8]) =
            *reinterpret_cast<const short8*>(&vb[((size_t)bh*S_ + s0 + row)*HD_ + c8]);
    }
    __syncthreads();
    #pragma unroll
    for (int i=0;i<2;i++){
        int d = (t>>3) + i*32;
        short8 o;
        #pragma unroll
        for (int j=0;j<8;j++) o[j] = tl[(c8+j)*72 + d];
        *reinterpret_cast<short8*>(&vt[((size_t)bh*HD_ + d)*S_ + s0 + c8]) = o;
    }
}

// ------------- fused attention v7 (proven 164us): bias C-init + gload_lds staging -------------
// LDS layout: XOR-swizzled content achieved via permuted GLOBAL source
// (lane ^ ((lane>>3)&7)) with linear LDS destination (guide m173 pattern).
__global__ __launch_bounds__(256, 4) void attn7_kernel(
    const short* __restrict__ qb, const short* __restrict__ kbuf,
    const short* __restrict__ vtg, const short* __restrict__ relb,
    const int* __restrict__ rowidx, short* __restrict__ ctxg)
{
    __shared__ alignas(16) char smem[32768];   // K dbuf [2][64][64], V dbuf [2][64][64]
    const int t = threadIdx.x;
    const int lane = t & 63, wid = t >> 6;
    const int hi = lane >> 5, lr = lane & 31, lr7 = lr & 7;
    const bool lo = (hi == 0);
    // XCD-aware swizzle: 16 q-tiles x 8 heads (same batch) per XCD
    const int id = blockIdx.x;
    const int g = (id & 7)*128 + (id >> 3);
    const int qt = g & 15, bh = g >> 4;
    const int h = bh & 15, b = bh >> 4;
    const int q = qt*128 + wid*32 + lr;

    // Q fragments (B-operand), already scaled by 0.125*log2(e)
    short8 qf[4];
    #pragma unroll
    for (int mm=0;mm<4;mm++)
        qf[mm] = *reinterpret_cast<const short8*>(&qb[((size_t)bh*S_ + q)*HD_ + mm*16 + hi*8]);

    int ridx = rowidx[b*S_ + q];
    ridx = ridx > 2039 ? 2039 : ridx;
    // pre-offset by 4*hi: all fragment extracts become static
    const short* relrow = relb + ((size_t)b<<22) + (size_t)ridx*2048 + 4*hi;

    float m_run = -3e38f, l_run = 0.f;
    f32x16 oa0 = {}, oa1 = {};

    const short* kg_base = kbuf + (size_t)bh*S_*HD_;
    const short* vg_base = vtg  + (size_t)bh*HD_*S_;

    // staging geometry: per wave, lane l loads chunk c = base + (l ^ ((l>>3)&7));
    // LDS dest linear (base + lane*16 by HW) -> content matches XOR-swizzled layout.
    const int pl = lane ^ ((lane>>3)&7);
    const int c0 = wid*64 + pl;
    const int c1 = c0 + 256;
    const size_t ks0 = (size_t)c0*8, ks1 = (size_t)c1*8;
    const size_t vs0 = (size_t)(c0>>3)*S_ + (size_t)(c0&7)*8;
    const size_t vs1 = (size_t)(c1>>3)*S_ + (size_t)(c1&7)*8;
    const int lb0 = wid*1024;
    const int lb1 = wid*1024 + 4096;

    // prologue: stage K/V tile 0 into buffer 0; load bias tile 0 into rbc
    gload16(kg_base + ks0, (short*)(smem + lb0));
    gload16(kg_base + ks1, (short*)(smem + lb1));
    gload16(vg_base + vs0, (short*)(smem + 16384 + lb0));
    gload16(vg_base + vs1, (short*)(smem + 16384 + lb1));
    short4v rbc[8], rbn[8];
    #pragma unroll
    for (int j=0;j<8;j++) rbc[j] = *reinterpret_cast<const short4v*>(relrow + j*8);
    __syncthreads();

    int cur = 0;
    const int NT = S_/64;
    for (int tt = 0; tt < NT; ++tt){
        const int kb0 = tt*64;
        // issue next-tile staging first (completion enforced by barrier at tile end)
        if (tt < NT-1){
            const short* kg = kg_base + (size_t)(kb0+64)*HD_;
            const short* vg = vg_base + (kb0+64);
            char* kd = smem + (cur^1)*8192;
            char* vd = smem + 16384 + (cur^1)*8192;
            gload16(kg + ks0, (short*)(kd + lb0));
            gload16(kg + ks1, (short*)(kd + lb1));
            gload16(vg + vs0, (short*)(vd + lb0));
            gload16(vg + vs1, (short*)(vd + lb1));
            const short* rr = relrow + kb0 + 64;
            #pragma unroll
            for (int j=0;j<8;j++) rbn[j] = *reinterpret_cast<const short4v*>(rr + j*8);
        }
        char* kb_lds = smem + cur*8192;
        char* vb_lds = smem + 16384 + cur*8192;

        // ---- C-init: bias goes in as the QK accumulator ----
        f32x16 p0, p1;
        #pragma unroll
        for (int g2=0; g2<4; g2++){
            #pragma unroll
            for (int i=0;i<4;i++){
                p0[4*g2+i] = bf2f(rbc[g2][i]);
                p1[4*g2+i] = bf2f(rbc[4+g2][i]);
            }
        }

        // ---- QK^T (swapped), scores come out fully scaled+biased ----
        __builtin_amdgcn_s_setprio(1);
        #pragma unroll
        for (int mm=0;mm<4;mm++){
            int swz = ((2*mm+hi) ^ lr7) << 4;
            short8 kf0 = *(const short8*)(kb_lds + lr*128 + swz);
            short8 kf1 = *(const short8*)(kb_lds + (32+lr)*128 + swz);
            p0 = __builtin_amdgcn_mfma_f32_32x32x16_bf16(kf0, qf[mm], p0, 0,0,0);
            p1 = __builtin_amdgcn_mfma_f32_32x32x16_bf16(kf1, qf[mm], p1, 0,0,0);
        }
        __builtin_amdgcn_s_setprio(0);

        // ---- online softmax with defer-max (max3 tree; full-swap only on rescale) ----
        float a0 = fmaxf(fmaxf(p0[0],p0[1]),p0[2]);
        float a1 = fmaxf(fmaxf(p0[3],p0[4]),p0[5]);
        float a2 = fmaxf(fmaxf(p0[6],p0[7]),p0[8]);
        float a3 = fmaxf(fmaxf(p0[9],p0[10]),p0[11]);
        float a4 = fmaxf(fmaxf(p0[12],p0[13]),p0[14]);
        float a5 = fmaxf(fmaxf(p0[15],p1[0]),p1[1]);
        float a6 = fmaxf(fmaxf(p1[2],p1[3]),p1[4]);
        float a7 = fmaxf(fmaxf(p1[5],p1[6]),p1[7]);
        float a8 = fmaxf(fmaxf(p1[8],p1[9]),p1[10]);
        float a9 = fmaxf(fmaxf(p1[11],p1[12]),p1[13]);
        float aa = fmaxf(p1[14],p1[15]);
        float b0v = fmaxf(fmaxf(a0,a1),a2);
        float b1v = fmaxf(fmaxf(a3,a4),a5);
        float b2v = fmaxf(fmaxf(a6,a7),a8);
        float b3v = fmaxf(a9,aa);
        float mt = fmaxf(fmaxf(b0v,b1v), fmaxf(b2v,b3v));
        if (__ballot(mt > m_run + 8.f) != 0ull){
            float mfull = fmaxf(mt, half_other(mt, lo));
            float mnew = fmaxf(m_run, mfull);
            float ef = exp2f(m_run - mnew);
            m_run = mnew;
            l_run *= ef;
            #pragma unroll
            for (int r=0;r<16;r++){ oa0[r]*=ef; oa1[r]*=ef; }
        }

        #pragma unroll
        for (int r=0;r<16;r++) p0[r] = exp2f(p0[r]-m_run);
        #pragma unroll
        for (int r=0;r<16;r++) p1[r] = exp2f(p1[r]-m_run);

        float s00 = (p0[0]+p0[1])+(p0[2]+p0[3]);
        float s01 = (p0[4]+p0[5])+(p0[6]+p0[7]);
        float s02 = (p0[8]+p0[9])+(p0[10]+p0[11]);
        float s03 = (p0[12]+p0[13])+(p0[14]+p0[15]);
        float s10 = (p1[0]+p1[1])+(p1[2]+p1[3]);
        float s11 = (p1[4]+p1[5])+(p1[6]+p1[7]);
        float s12 = (p1[8]+p1[9])+(p1[10]+p1[11]);
        float s13 = (p1[12]+p1[13])+(p1[14]+p1[15]);
        float rs = ((s00+s01)+(s02+s03)) + ((s10+s11)+(s12+s13));
        rs += half_other(rs, lo);
        l_run += rs;

        // ---- P -> bf16 B-fragments via cvt_pk + permlane32_swap ----
        short8 pf[4];
        #pragma unroll
        for (int kb=0;kb<4;kb++){
            const f32x16& P = (kb<2) ? p0 : p1;
            const int r0 = 8*(kb&1);
            int X0 = cvtpk_bf16(P[r0+0], P[r0+1]);
            int Y0 = cvtpk_bf16(P[r0+2], P[r0+3]);
            int X1 = cvtpk_bf16(P[r0+4], P[r0+5]);
            int Y1 = cvtpk_bf16(P[r0+6], P[r0+7]);
            int2v w02 = __builtin_amdgcn_permlane32_swap(X0, X1, false, false);
            int2v w13 = __builtin_amdgcn_permlane32_swap(Y0, Y1, false, false);
            pf[kb] = __builtin_bit_cast(short8, (int4v){w02.x, w13.x, w02.y, w13.y});
        }

        // ---- PV (swapped) ----
        __builtin_amdgcn_s_setprio(1);
        #pragma unroll
        for (int kb=0;kb<4;kb++){
            int swz = ((2*kb+hi) ^ lr7) << 4;
            short8 vf0 = *(const short8*)(vb_lds + lr*128 + swz);
            short8 vf1 = *(const short8*)(vb_lds + (32+lr)*128 + swz);
            oa0 = __builtin_amdgcn_mfma_f32_32x32x16_bf16(vf0, pf[kb], oa0, 0,0,0);
            oa1 = __builtin_amdgcn_mfma_f32_32x32x16_bf16(vf1, pf[kb], oa1, 0,0,0);
        }
        __builtin_amdgcn_s_setprio(0);

        // ---- rotate bias regs; barrier completes the in-flight LDS stage ----
        if (tt < NT-1){
            #pragma unroll
            for (int j=0;j<8;j++) rbc[j] = rbn[j];
        }
        __syncthreads();
        cur ^= 1;
    }

    // ---- epilogue: O/l -> bf16, LDS transpose stage, coalesced store ----
    char* ost = smem + wid*4096;
    float invl = 1.f / l_run;
    #pragma unroll
    for (int db=0; db<2; db++){
        const f32x16& O = (db==0) ? oa0 : oa1;
        #pragma unroll
        for (int g2=0; g2<4; g2++){
            int w0 = cvtpk_bf16(O[4*g2+0]*invl, O[4*g2+1]*invl);
            int w1 = cvtpk_bf16(O[4*g2+2]*invl, O[4*g2+3]*invl);
            int by = lr*128 + (((4*db+g2) ^ lr7)<<4) + hi*8;
            *reinterpret_cast<int2v*>(ost + by) = (int2v){w0, w1};
        }
    }
    __syncthreads();
    const size_t obase = ((size_t)b*S_ + qt*128 + wid*32)*HID_ + h*HD_;
    #pragma unroll
    for (int i=0;i<4;i++){
        int row = i*8 + (lane>>3);
        int c = lane&7;
        short8 v = *(const short8*)(ost + row*128 + ((c ^ (row&7))<<4));
        *reinterpret_cast<short8*>(&ctxg[obase + (size_t)row*HID_ + c*8]) = v;
    }
}

// ------------- residual + LayerNorm (og bf16) -------------
__global__ __launch_bounds__(256) void ln_kernel(const short* __restrict__ og,
    const float* __restrict__ hidden, const float* __restrict__ g,
    const float* __restrict__ bb, float* __restrict__ out){
    int row = blockIdx.x;
    int t = threadIdx.x;
    short4v ov = *reinterpret_cast<const short4v*>(&og[(size_t)row*HID_ + t*4]);
    float4 hv = *reinterpret_cast<const float4*>(&hidden[(size_t)row*HID_ + t*4]);
    float x0 = bf2f(ov.x) + hv.x, x1 = bf2f(ov.y) + hv.y;
    float x2 = bf2f(ov.z) + hv.z, x3 = bf2f(ov.w) + hv.w;
    float s = x0+x1+x2+x3;
    float qq = x0*x0+x1*x1+x2*x2+x3*x3;
    #pragma unroll
    for (int off=1;off<64;off<<=1){ s += __shfl_xor(s,off); qq += __shfl_xor(qq,off); }
    __shared__ float rs[4], rq[4];
    int lane = t&63, wid = t>>6;
    if (lane==0){ rs[wid]=s; rq[wid]=qq; }
    __syncthreads();
    s = rs[0]+rs[1]+rs[2]+rs[3];
    qq = rq[0]+rq[1]+rq[2]+rq[3];
    float mu  = s * (1.f/1024.f);
    float var = qq * (1.f/1024.f) - mu*mu;
    float inv = rsqrtf(var + 1e-12f);
    float4 gv = *reinterpret_cast<const float4*>(&g[t*4]);
    float4 bv = *reinterpret_cast<const float4*>(&bb[t*4]);
    float4 y;
    y.x = (x0-mu)*inv*gv.x + bv.x;
    y.y = (x1-mu)*inv*gv.y + bv.y;
    y.z = (x2-mu)*inv*gv.z + bv.z;
    y.w = (x3-mu)*inv*gv.w + bv.w;
    *reinterpret_cast<float4*>(&out[(size_t)row*HID_ + t*4]) = y;
}

extern "C" void kernel_launch(void* const* d_in, const int* in_sizes, int n_in,
                              void* d_out, int out_size, void* d_ws, size_t ws_size,
                              hipStream_t stream){
    const float* hidden = (const float*)d_in[0];
    const float* amask  = (const float*)d_in[1];
    const float* mmask  = (const float*)d_in[2];
    const float* Wq = (const float*)d_in[3];
    const float* bq = (const float*)d_in[4];
    const float* Wk = (const float*)d_in[5];
    const float* bk = (const float*)d_in[6];
    const float* Wv = (const float*)d_in[7];
    const float* bv = (const float*)d_in[8];
    const float* rel = (const float*)d_in[9];
    const float* Wd = (const float*)d_in[10];
    const float* bd = (const float*)d_in[11];
    const float* lng = (const float*)d_in[12];
    const float* lnb = (const float*)d_in[13];
    float* out = (float*)d_out;

    char* ws = (char*)d_ws;
    // layout (104 MB total):
    short* xb   = (short*)(ws);                      // 0-16MB   bf16 hidden (dead after QKV gemm)
    short* vtb  = (short*)(ws);                      // 0-16MB   v [b,h,d,s] (after xb dies)
    short* wt   = (short*)(ws + (16u<<20));          // 16-24MB  4x bf16 W^T (QKV fused + Wd)
    short* qb   = (short*)(ws + (24u<<20));          // 24-40MB  q [b,h,s,d] (pre-scaled by CQ)
    short* kb2  = (short*)(ws + (40u<<20));          // 40-56MB  k [b,h,s,d]
    short* vb   = (short*)(ws + (56u<<20));          // 56-72MB  v [b,h,s,d] (dead after transpose_v)
    short* ctx  = (short*)(ws + (56u<<20));          // 56-72MB  ctx (after vb dies)
    short* relb = (short*)(ws + (72u<<20));          // 72-104MB deduped bias rows [4][<=2040][2048] bf16
    short* og   = (short*)(ws + (24u<<20));          // 24-40MB  bf16, aliases qb (dead after attn)
    int* rowidx = (int*)(ws + (104u<<20) - (32u<<10)); // 32KB, tail of relb region (rows >2039 unused)

    cast_x_kernel<<<8192, 256, 0, stream>>>(hidden, xb, M_*HID_/4);
    dim3 gw(16,16);
    castT_w_kernel<<<gw, 256, 0, stream>>>(Wq, wt + 0*(1u<<20));
    castT_w_kernel<<<gw, 256, 0, stream>>>(Wk, wt + 1*(1u<<20));
    castT_w_kernel<<<gw, 256, 0, stream>>>(Wv, wt + 2*(1u<<20));
    castT_w_kernel<<<gw, 256, 0, stream>>>(Wd, wt + 3*(1u<<20));
    idx_kernel<<<4, 64, 0, stream>>>(mmask, rowidx);
    relb2_kernel<<<2048, 256, 0, stream>>>(rel, mmask, amask, rowidx, relb);
    // fused QKV gemm: N=3072 over concatenated W^T (last use of xb)
    gemm_bt<0><<<1536, 256, 0, stream>>>(xb, wt, bq, bk, bv, qb, kb2, vb);
    // xb dead -> vtb takes its region; vb dead after this
    transpose_v<<<dim3(32,NH_,B_), 256, 0, stream>>>(vb, vtb);
    attn7_kernel<<<1024, 256, 0, stream>>>(qb, kb2, vtb, relb, rowidx, ctx);
    gemm_bt<1><<<512, 256, 0, stream>>>(ctx, wt + 3*(1u<<20), bd, nullptr, nullptr,
                                        og, nullptr, nullptr);
    ln_kernel<<<8192, 256, 0, stream>>>(og, hidden, lng, lnb, out);
}

// Round 16
// 260.686 us; speedup vs baseline: 1.9129x; 1.0702x over previous
//
#include <hip/hip_runtime.h>
#include <hip/hip_bf16.h>

#define B_ 4
#define S_ 2048
#define HID_ 1024
#define NH_ 16
#define HD_ 64
#define M_ (B_*S_)   // 8192

typedef __attribute__((ext_vector_type(8))) short short8;
typedef __attribute__((ext_vector_type(4))) float f32x4;
typedef __attribute__((ext_vector_type(16))) float f32x16;
typedef __attribute__((ext_vector_type(4))) short short4v;
typedef __attribute__((ext_vector_type(2))) int int2v;
typedef __attribute__((ext_vector_type(4))) int int4v;

static __device__ __forceinline__ short bf16_of(float f){
    union { __hip_bfloat16 h; short s; } u;
    u.h = __float2bfloat16(f);
    return u.s;
}

static __device__ __forceinline__ float bf2f(short s){
    return __int_as_float(((int)(unsigned short)s) << 16);
}

static __device__ __forceinline__ int cvtpk_bf16(float lo, float hi){
    int r;
    asm("v_cvt_pk_bf16_f32 %0, %1, %2" : "=v"(r) : "v"(lo), "v"(hi));
    return r;
}

// partner value across the lane<32 / lane>=32 halves
static __device__ __forceinline__ float half_other(float v, bool lo){
    int2v r = __builtin_amdgcn_permlane32_swap(__float_as_int(v), __float_as_int(v), false, false);
    return __int_as_float(lo ? r.y : r.x);
}

// async global->LDS, 16B per lane; LDS dest must be wave-uniform base (HW adds lane*16)
static __device__ __forceinline__ void gload16(const short* g, short* l){
    __builtin_amdgcn_global_load_lds(
        (const __attribute__((address_space(1))) void*)(g),
        (__attribute__((address_space(3))) void*)(l),
        16, 0, 0);
}

// ---------------- cast hidden f32 -> bf16 ----------------
__global__ __launch_bounds__(256) void cast_x_kernel(const float* __restrict__ x,
                                                     short* __restrict__ xb, int n4){
    int i = blockIdx.x*blockDim.x + threadIdx.x;
    if (i >= n4) return;
    float4 f = reinterpret_cast<const float4*>(x)[i];
    short4v o;
    o.x = bf16_of(f.x); o.y = bf16_of(f.y); o.z = bf16_of(f.z); o.w = bf16_of(f.w);
    reinterpret_cast<short4v*>(xb)[i] = o;
}

// ------------- cast + transpose all 4 weights: Wt[n][k] = W[k][n], bf16 -------------
__global__ __launch_bounds__(256) void castT_all_kernel(const float* __restrict__ W0,
        const float* __restrict__ W1, const float* __restrict__ W2,
        const float* __restrict__ W3, short* __restrict__ WtAll){
    const int z = blockIdx.z;
    const float* W = (z==0) ? W0 : (z==1) ? W1 : (z==2) ? W2 : W3;
    short* Wt = WtAll + (size_t)z*(1u<<20);
    __shared__ float tl[64][65];
    int k0 = blockIdx.x*64, n0 = blockIdx.y*64;
    int t = threadIdx.x;
    int r = t>>2, cg = (t&3)*16;
    #pragma unroll
    for (int j=0;j<4;j++){
        float4 f = *reinterpret_cast<const float4*>(&W[(k0+r)*HID_ + n0 + cg + j*4]);
        tl[r][cg+j*4+0]=f.x; tl[r][cg+j*4+1]=f.y; tl[r][cg+j*4+2]=f.z; tl[r][cg+j*4+3]=f.w;
    }
    __syncthreads();
    short8 o0, o1;
    #pragma unroll
    for (int j=0;j<8;j++) o0[j] = bf16_of(tl[cg+j][r]);
    #pragma unroll
    for (int j=0;j<8;j++) o1[j] = bf16_of(tl[cg+8+j][r]);
    *reinterpret_cast<short8*>(&Wt[(n0+r)*HID_ + k0 + cg])     = o0;
    *reinterpret_cast<short8*>(&Wt[(n0+r)*HID_ + k0 + cg + 8]) = o1;
}

// ------------- rowidx: per-(b,q) bias-row index (0 = shared amask-only row) -------------
__global__ void idx_kernel(const float* __restrict__ mm_, int* __restrict__ rowidx){
    int b = blockIdx.x;
    int lane = threadIdx.x;  // 64 threads
    const float* m = mm_ + b*S_;
    uint64_t lmask = (lane==0) ? 0ull : (~0ull >> (64-lane));
    int base = 1;
    for (int c=0;c<S_;c+=64){
        bool act = m[c+lane] != 0.f;
        uint64_t bal = __ballot(act);
        int r = __popcll(bal & lmask);
        rowidx[b*S_ + c + lane] = act ? (base + r) : 0;
        base += __popcll(bal);
    }
}

// ------------- deduped bias rows (log2e units, bf16) -------------
__global__ __launch_bounds__(256) void relb2_kernel(const float* __restrict__ rel,
        const float* __restrict__ mm_, const float* __restrict__ am_,
        const int* __restrict__ rowidx, short* __restrict__ relb){
    const float C = 0.1f * 1.44269504f;
    const float L = -10000.f * 1.44269504f;
    const int q = blockIdx.x;
    const int c0 = threadIdx.x * 8;
    float4 r0 = *reinterpret_cast<const float4*>(rel + (size_t)q*2048 + c0);
    float4 r1 = *reinterpret_cast<const float4*>(rel + (size_t)q*2048 + c0 + 4);
    #pragma unroll
    for (int b=0;b<B_;b++){
        float4 a0v = *reinterpret_cast<const float4*>(am_ + b*S_ + c0);
        float4 a1v = *reinterpret_cast<const float4*>(am_ + b*S_ + c0 + 4);
        float amt0 = (1.f-a0v.x)*L, amt1 = (1.f-a0v.y)*L;
        float amt2 = (1.f-a0v.z)*L, amt3 = (1.f-a0v.w)*L;
        float amt4 = (1.f-a1v.x)*L, amt5 = (1.f-a1v.y)*L;
        float amt6 = (1.f-a1v.z)*L, amt7 = (1.f-a1v.w)*L;
        if (q == 0){
            short8 o;
            o[0]=bf16_of(amt0); o[1]=bf16_of(amt1); o[2]=bf16_of(amt2); o[3]=bf16_of(amt3);
            o[4]=bf16_of(amt4); o[5]=bf16_of(amt5); o[6]=bf16_of(amt6); o[7]=bf16_of(amt7);
            *reinterpret_cast<short8*>(relb + ((size_t)b<<22) + c0) = o;
        }
        float mq = mm_[b*S_ + q];
        if (mq != 0.f){
            int ridx = rowidx[b*S_ + q];
            ridx = ridx > 2039 ? 2039 : ridx;
            float mqC = mq * C;
            float4 k0v = *reinterpret_cast<const float4*>(mm_ + b*S_ + c0);
            float4 k1v = *reinterpret_cast<const float4*>(mm_ + b*S_ + c0 + 4);
            short8 o;
            o[0]=bf16_of(fmaf(mqC*k0v.x, r0.x, amt0));
            o[1]=bf16_of(fmaf(mqC*k0v.y, r0.y, amt1));
            o[2]=bf16_of(fmaf(mqC*k0v.z, r0.z, amt2));
            o[3]=bf16_of(fmaf(mqC*k0v.w, r0.w, amt3));
            o[4]=bf16_of(fmaf(mqC*k1v.x, r1.x, amt4));
            o[5]=bf16_of(fmaf(mqC*k1v.y, r1.y, amt5));
            o[6]=bf16_of(fmaf(mqC*k1v.z, r1.z, amt6));
            o[7]=bf16_of(fmaf(mqC*k1v.w, r1.w, amt7));
            *reinterpret_cast<short8*>(relb + ((size_t)b<<22) + (size_t)ridx*2048 + c0) = o;
        }
    }
}

// ------------- GEMM v2: BK=64, XOR-swizzled LDS, global_load_lds staging -------------
// OMODE 0: fused QKV (Wt [3072][1024]); Q/K headed bf16 [b,h,s,d] (Q pre-scaled by CQ);
//          V written TRANSPOSED to [b,h,d,s] (packed 8B stores).
// OMODE 1: single (Wt [1024][1024]); bf16 flat [m][n] to o0.
// LDS [128][64] bf16, content XOR-swizzled (byte ^= ((row&7)<<4)) via pre-permuted
// global source (same m173 pattern as attn7); reads use matching swizzled offsets.
template<int OMODE>
__global__ __launch_bounds__(256) void gemm_bt(const short* __restrict__ A,
        const short* __restrict__ Wt, const float* __restrict__ bb0,
        const float* __restrict__ bb1, const float* __restrict__ bb2,
        short* __restrict__ o0, short* __restrict__ o1, short* __restrict__ o2){
    __shared__ short As[128*64];   // 16 KB
    __shared__ short Bs[128*64];   // 16 KB
    int tid = threadIdx.x;
    int lane = tid & 63, wid = tid >> 6;
    int wm = wid >> 1, wn = wid & 1;
    int lr = lane & 15, lg = lane >> 4;
    // XCD-aware swizzle: per XCD, A-panel (8 m-tiles) stays L2-resident
    const int id = blockIdx.x;
    const int s_ = id >> 3;
    const int ntile = s_ >> 3;
    const int mtile = (id & 7)*8 + (s_ & 7);
    const int m0 = mtile*128, n0 = ntile*128;

    // staging: chunk c = wid*256 + i*64 + lane; LDS linear dest c*16B (HW adds lane*16);
    // source pre-permuted so LDS content is swizzled: src col8 = (lane&7)^(lane>>3)
    const int srow = wid*32 + (lane>>3);
    const int scol = ((lane&7) ^ (lane>>3))*8;
    const short* Ab = A  + (size_t)(m0+srow)*1024 + scol;
    const short* Bb = Wt + (size_t)(n0+srow)*1024 + scol;
    short* lA = As + wid*2048;   // + i*512 per issue (wave-uniform)
    short* lB = Bs + wid*2048;

    f32x4 acc[4][4] = {};
    for (int kk = 0; kk < 1024; kk += 64){
        #pragma unroll
        for (int i=0;i<4;i++){
            gload16(Ab + kk + i*8192, lA + i*512);
            gload16(Bb + kk + i*8192, lB + i*512);
        }
        __syncthreads();   // drains vmcnt before barrier (compiler-inserted)
        #pragma unroll
        for (int t=0;t<2;t++){
            short8 af[4], bfr[4];
            #pragma unroll
            for (int x=0;x<4;x++){
                int ra = wm*64 + x*16 + lr;
                int rb = wn*64 + x*16 + lr;
                int sw = ((t*4+lg) ^ (lr&7)) << 4;
                af[x]  = *reinterpret_cast<const short8*>((const char*)As + ra*128 + sw);
                bfr[x] = *reinterpret_cast<const short8*>((const char*)Bs + rb*128 + sw);
            }
            #pragma unroll
            for (int mi=0;mi<4;mi++)
                #pragma unroll
                for (int ni=0;ni<4;ni++)
                    acc[mi][ni] = __builtin_amdgcn_mfma_f32_16x16x32_bf16(af[mi], bfr[ni], acc[mi][ni], 0,0,0);
        }
        __syncthreads();
    }
    #pragma unroll
    for (int mi=0;mi<4;mi++){
      #pragma unroll
      for (int ni=0;ni<4;ni++){
        int colg = n0 + wn*64 + ni*16 + lr;
        const float* bp; short* op; int cc; int sel = 0;
        if (OMODE == 0){
            sel = colg >> 10; cc = colg & 1023;
            bp = sel==0 ? bb0 : (sel==1 ? bb1 : bb2);
            op = sel==0 ? o0 : (sel==1 ? o1 : o2);
        } else { bp = bb0; cc = colg; op = o0; }
        float bv = bp[cc];
        int rbase = m0 + wm*64 + mi*16 + lg*4;     // 4 consecutive rows, same batch
        if (OMODE == 0 && sel == 2){
            // V: write transposed [b,h,d,s], packed 4 consecutive s (8B store)
            int bidx = rbase >> 11, s0v = rbase & 2047;
            int hh = cc >> 6, d = cc & 63;
            short4v vv;
            #pragma unroll
            for (int r=0;r<4;r++) vv[r] = bf16_of(acc[mi][ni][r] + bv);
            *reinterpret_cast<short4v*>(&op[(((size_t)bidx*NH_ + hh)*HD_ + d)*S_ + s0v]) = vv;
        } else {
            #pragma unroll
            for (int r=0;r<4;r++){
                int rowg = rbase + r;
                float v = acc[mi][ni][r] + bv;
                if (OMODE == 0){
                    if (sel == 0) v *= 0.18033688f;   // Q pre-scaled by 0.125*log2(e)
                    int bidx = rowg >> 11, ss = rowg & 2047;
                    int hh = cc >> 6, d = cc & 63;
                    op[(((size_t)bidx*NH_ + hh)*S_ + ss)*HD_ + d] = bf16_of(v);
                } else {
                    op[(size_t)rowg*1024 + colg] = bf16_of(v);
                }
            }
        }
      }
    }
}

// ------------- fused attention v7 (proven 164us): bias C-init + gload_lds staging -------------
// LDS layout: XOR-swizzled content achieved via permuted GLOBAL source
// (lane ^ ((lane>>3)&7)) with linear LDS destination (guide m173 pattern).
__global__ __launch_bounds__(256, 4) void attn7_kernel(
    const short* __restrict__ qb, const short* __restrict__ kbuf,
    const short* __restrict__ vtg, const short* __restrict__ relb,
    const int* __restrict__ rowidx, short* __restrict__ ctxg)
{
    __shared__ alignas(16) char smem[32768];   // K dbuf [2][64][64], V dbuf [2][64][64]
    const int t = threadIdx.x;
    const int lane = t & 63, wid = t >> 6;
    const int hi = lane >> 5, lr = lane & 31, lr7 = lr & 7;
    const bool lo = (hi == 0);
    // XCD-aware swizzle: 16 q-tiles x 8 heads (same batch) per XCD
    const int id = blockIdx.x;
    const int g = (id & 7)*128 + (id >> 3);
    const int qt = g & 15, bh = g >> 4;
    const int h = bh & 15, b = bh >> 4;
    const int q = qt*128 + wid*32 + lr;

    // Q fragments (B-operand), already scaled by 0.125*log2(e)
    short8 qf[4];
    #pragma unroll
    for (int mm=0;mm<4;mm++)
        qf[mm] = *reinterpret_cast<const short8*>(&qb[((size_t)bh*S_ + q)*HD_ + mm*16 + hi*8]);

    int ridx = rowidx[b*S_ + q];
    ridx = ridx > 2039 ? 2039 : ridx;
    // pre-offset by 4*hi: all fragment extracts become static
    const short* relrow = relb + ((size_t)b<<22) + (size_t)ridx*2048 + 4*hi;

    float m_run = -3e38f, l_run = 0.f;
    f32x16 oa0 = {}, oa1 = {};

    const short* kg_base = kbuf + (size_t)bh*S_*HD_;
    const short* vg_base = vtg  + (size_t)bh*HD_*S_;

    // staging geometry: per wave, lane l loads chunk c = base + (l ^ ((l>>3)&7));
    // LDS dest linear (base + lane*16 by HW) -> content matches XOR-swizzled layout.
    const int pl = lane ^ ((lane>>3)&7);
    const int c0 = wid*64 + pl;
    const int c1 = c0 + 256;
    const size_t ks0 = (size_t)c0*8, ks1 = (size_t)c1*8;
    const size_t vs0 = (size_t)(c0>>3)*S_ + (size_t)(c0&7)*8;
    const size_t vs1 = (size_t)(c1>>3)*S_ + (size_t)(c1&7)*8;
    const int lb0 = wid*1024;
    const int lb1 = wid*1024 + 4096;

    // prologue: stage K/V tile 0 into buffer 0; load bias tile 0 into rbc
    gload16(kg_base + ks0, (short*)(smem + lb0));
    gload16(kg_base + ks1, (short*)(smem + lb1));
    gload16(vg_base + vs0, (short*)(smem + 16384 + lb0));
    gload16(vg_base + vs1, (short*)(smem + 16384 + lb1));
    short4v rbc[8], rbn[8];
    #pragma unroll
    for (int j=0;j<8;j++) rbc[j] = *reinterpret_cast<const short4v*>(relrow + j*8);
    __syncthreads();

    int cur = 0;
    const int NT = S_/64;
    for (int tt = 0; tt < NT; ++tt){
        const int kb0 = tt*64;
        // issue next-tile staging first (completion enforced by barrier at tile end)
        if (tt < NT-1){
            const short* kg = kg_base + (size_t)(kb0+64)*HD_;
            const short* vg = vg_base + (kb0+64);
            char* kd = smem + (cur^1)*8192;
            char* vd = smem + 16384 + (cur^1)*8192;
            gload16(kg + ks0, (short*)(kd + lb0));
            gload16(kg + ks1, (short*)(kd + lb1));
            gload16(vg + vs0, (short*)(vd + lb0));
            gload16(vg + vs1, (short*)(vd + lb1));
            const short* rr = relrow + kb0 + 64;
            #pragma unroll
            for (int j=0;j<8;j++) rbn[j] = *reinterpret_cast<const short4v*>(rr + j*8);
        }
        char* kb_lds = smem + cur*8192;
        char* vb_lds = smem + 16384 + cur*8192;

        // ---- C-init: bias goes in as the QK accumulator ----
        f32x16 p0, p1;
        #pragma unroll
        for (int g2=0; g2<4; g2++){
            #pragma unroll
            for (int i=0;i<4;i++){
                p0[4*g2+i] = bf2f(rbc[g2][i]);
                p1[4*g2+i] = bf2f(rbc[4+g2][i]);
            }
        }

        // ---- QK^T (swapped), scores come out fully scaled+biased ----
        __builtin_amdgcn_s_setprio(1);
        #pragma unroll
        for (int mm=0;mm<4;mm++){
            int swz = ((2*mm+hi) ^ lr7) << 4;
            short8 kf0 = *(const short8*)(kb_lds + lr*128 + swz);
            short8 kf1 = *(const short8*)(kb_lds + (32+lr)*128 + swz);
            p0 = __builtin_amdgcn_mfma_f32_32x32x16_bf16(kf0, qf[mm], p0, 0,0,0);
            p1 = __builtin_amdgcn_mfma_f32_32x32x16_bf16(kf1, qf[mm], p1, 0,0,0);
        }
        __builtin_amdgcn_s_setprio(0);

        // ---- online softmax with defer-max (max3 tree; full-swap only on rescale) ----
        float a0 = fmaxf(fmaxf(p0[0],p0[1]),p0[2]);
        float a1 = fmaxf(fmaxf(p0[3],p0[4]),p0[5]);
        float a2 = fmaxf(fmaxf(p0[6],p0[7]),p0[8]);
        float a3 = fmaxf(fmaxf(p0[9],p0[10]),p0[11]);
        float a4 = fmaxf(fmaxf(p0[12],p0[13]),p0[14]);
        float a5 = fmaxf(fmaxf(p0[15],p1[0]),p1[1]);
        float a6 = fmaxf(fmaxf(p1[2],p1[3]),p1[4]);
        float a7 = fmaxf(fmaxf(p1[5],p1[6]),p1[7]);
        float a8 = fmaxf(fmaxf(p1[8],p1[9]),p1[10]);
        float a9 = fmaxf(fmaxf(p1[11],p1[12]),p1[13]);
        float aa = fmaxf(p1[14],p1[15]);
        float b0v = fmaxf(fmaxf(a0,a1),a2);
        float b1v = fmaxf(fmaxf(a3,a4),a5);
        float b2v = fmaxf(fmaxf(a6,a7),a8);
        float b3v = fmaxf(a9,aa);
        float mt = fmaxf(fmaxf(b0v,b1v), fmaxf(b2v,b3v));
        if (__ballot(mt > m_run + 8.f) != 0ull){
            float mfull = fmaxf(mt, half_other(mt, lo));
            float mnew = fmaxf(m_run, mfull);
            float ef = exp2f(m_run - mnew);
            m_run = mnew;
            l_run *= ef;
            #pragma unroll
            for (int r=0;r<16;r++){ oa0[r]*=ef; oa1[r]*=ef; }
        }

        #pragma unroll
        for (int r=0;r<16;r++) p0[r] = exp2f(p0[r]-m_run);
        #pragma unroll
        for (int r=0;r<16;r++) p1[r] = exp2f(p1[r]-m_run);

        float s00 = (p0[0]+p0[1])+(p0[2]+p0[3]);
        float s01 = (p0[4]+p0[5])+(p0[6]+p0[7]);
        float s02 = (p0[8]+p0[9])+(p0[10]+p0[11]);
        float s03 = (p0[12]+p0[13])+(p0[14]+p0[15]);
        float s10 = (p1[0]+p1[1])+(p1[2]+p1[3]);
        float s11 = (p1[4]+p1[5])+(p1[6]+p1[7]);
        float s12 = (p1[8]+p1[9])+(p1[10]+p1[11]);
        float s13 = (p1[12]+p1[13])+(p1[14]+p1[15]);
        float rs = ((s00+s01)+(s02+s03)) + ((s10+s11)+(s12+s13));
        rs += half_other(rs, lo);
        l_run += rs;

        // ---- P -> bf16 B-fragments via cvt_pk + permlane32_swap ----
        short8 pf[4];
        #pragma unroll
        for (int kb=0;kb<4;kb++){
            const f32x16& P = (kb<2) ? p0 : p1;
            const int r0 = 8*(kb&1);
            int X0 = cvtpk_bf16(P[r0+0], P[r0+1]);
            int Y0 = cvtpk_bf16(P[r0+2], P[r0+3]);
            int X1 = cvtpk_bf16(P[r0+4], P[r0+5]);
            int Y1 = cvtpk_bf16(P[r0+6], P[r0+7]);
            int2v w02 = __builtin_amdgcn_permlane32_swap(X0, X1, false, false);
            int2v w13 = __builtin_amdgcn_permlane32_swap(Y0, Y1, false, false);
            pf[kb] = __builtin_bit_cast(short8, (int4v){w02.x, w13.x, w02.y, w13.y});
        }

        // ---- PV (swapped) ----
        __builtin_amdgcn_s_setprio(1);
        #pragma unroll
        for (int kb=0;kb<4;kb++){
            int swz = ((2*kb+hi) ^ lr7) << 4;
            short8 vf0 = *(const short8*)(vb_lds + lr*128 + swz);
            short8 vf1 = *(const short8*)(vb_lds + (32+lr)*128 + swz);
            oa0 = __builtin_amdgcn_mfma_f32_32x32x16_bf16(vf0, pf[kb], oa0, 0,0,0);
            oa1 = __builtin_amdgcn_mfma_f32_32x32x16_bf16(vf1, pf[kb], oa1, 0,0,0);
        }
        __builtin_amdgcn_s_setprio(0);

        // ---- rotate bias regs; barrier completes the in-flight LDS stage ----
        if (tt < NT-1){
            #pragma unroll
            for (int j=0;j<8;j++) rbc[j] = rbn[j];
        }
        __syncthreads();
        cur ^= 1;
    }

    // ---- epilogue: O/l -> bf16, LDS transpose stage, coalesced store ----
    char* ost = smem + wid*4096;
    float invl = 1.f / l_run;
    #pragma unroll
    for (int db=0; db<2; db++){
        const f32x16& O = (db==0) ? oa0 : oa1;
        #pragma unroll
        for (int g2=0; g2<4; g2++){
            int w0 = cvtpk_bf16(O[4*g2+0]*invl, O[4*g2+1]*invl);
            int w1 = cvtpk_bf16(O[4*g2+2]*invl, O[4*g2+3]*invl);
            int by = lr*128 + (((4*db+g2) ^ lr7)<<4) + hi*8;
            *reinterpret_cast<int2v*>(ost + by) = (int2v){w0, w1};
        }
    }
    __syncthreads();
    const size_t obase = ((size_t)b*S_ + qt*128 + wid*32)*HID_ + h*HD_;
    #pragma unroll
    for (int i=0;i<4;i++){
        int row = i*8 + (lane>>3);
        int c = lane&7;
        short8 v = *(const short8*)(ost + row*128 + ((c ^ (row&7))<<4));
        *reinterpret_cast<short8*>(&ctxg[obase + (size_t)row*HID_ + c*8]) = v;
    }
}

// ------------- residual + LayerNorm (og bf16) -------------
__global__ __launch_bounds__(256) void ln_kernel(const short* __restrict__ og,
    const float* __restrict__ hidden, const float* __restrict__ g,
    const float* __restrict__ bb, float* __restrict__ out){
    int row = blockIdx.x;
    int t = threadIdx.x;
    short4v ov = *reinterpret_cast<const short4v*>(&og[(size_t)row*HID_ + t*4]);
    float4 hv = *reinterpret_cast<const float4*>(&hidden[(size_t)row*HID_ + t*4]);
    float x0 = bf2f(ov.x) + hv.x, x1 = bf2f(ov.y) + hv.y;
    float x2 = bf2f(ov.z) + hv.z, x3 = bf2f(ov.w) + hv.w;
    float s = x0+x1+x2+x3;
    float qq = x0*x0+x1*x1+x2*x2+x3*x3;
    #pragma unroll
    for (int off=1;off<64;off<<=1){ s += __shfl_xor(s,off); qq += __shfl_xor(qq,off); }
    __shared__ float rs[4], rq[4];
    int lane = t&63, wid = t>>6;
    if (lane==0){ rs[wid]=s; rq[wid]=qq; }
    __syncthreads();
    s = rs[0]+rs[1]+rs[2]+rs[3];
    qq = rq[0]+rq[1]+rq[2]+rq[3];
    float mu  = s * (1.f/1024.f);
    float var = qq * (1.f/1024.f) - mu*mu;
    float inv = rsqrtf(var + 1e-12f);
    float4 gv = *reinterpret_cast<const float4*>(&g[t*4]);
    float4 bv = *reinterpret_cast<const float4*>(&bb[t*4]);
    float4 y;
    y.x = (x0-mu)*inv*gv.x + bv.x;
    y.y = (x1-mu)*inv*gv.y + bv.y;
    y.z = (x2-mu)*inv*gv.z + bv.z;
    y.w = (x3-mu)*inv*gv.w + bv.w;
    *reinterpret_cast<float4*>(&out[(size_t)row*HID_ + t*4]) = y;
}

extern "C" void kernel_launch(void* const* d_in, const int* in_sizes, int n_in,
                              void* d_out, int out_size, void* d_ws, size_t ws_size,
                              hipStream_t stream){
    const float* hidden = (const float*)d_in[0];
    const float* amask  = (const float*)d_in[1];
    const float* mmask  = (const float*)d_in[2];
    const float* Wq = (const float*)d_in[3];
    const float* bq = (const float*)d_in[4];
    const float* Wk = (const float*)d_in[5];
    const float* bk = (const float*)d_in[6];
    const float* Wv = (const float*)d_in[7];
    const float* bv = (const float*)d_in[8];
    const float* rel = (const float*)d_in[9];
    const float* Wd = (const float*)d_in[10];
    const float* bd = (const float*)d_in[11];
    const float* lng = (const float*)d_in[12];
    const float* lnb = (const float*)d_in[13];
    float* out = (float*)d_out;

    char* ws = (char*)d_ws;
    // layout (104 MB total):
    short* xb   = (short*)(ws);                      // 0-16MB   bf16 hidden (alive through QKV gemm)
    short* ctx  = (short*)(ws);                      // 0-16MB   ctx (after xb dies)
    short* wt   = (short*)(ws + (16u<<20));          // 16-24MB  4x bf16 W^T (QKV fused + Wd)
    short* qb   = (short*)(ws + (24u<<20));          // 24-40MB  q [b,h,s,d] (pre-scaled by CQ)
    short* kb2  = (short*)(ws + (40u<<20));          // 40-56MB  k [b,h,s,d]
    short* vtb  = (short*)(ws + (56u<<20));          // 56-72MB  v [b,h,d,s] (written directly by gemm)
    short* relb = (short*)(ws + (72u<<20));          // 72-104MB deduped bias rows [4][<=2040][2048] bf16
    short* og   = (short*)(ws + (24u<<20));          // 24-40MB  bf16, aliases qb (dead after attn)
    int* rowidx = (int*)(ws + (104u<<20) - (32u<<10)); // 32KB, tail of relb region (rows >2039 unused)

    cast_x_kernel<<<8192, 256, 0, stream>>>(hidden, xb, M_*HID_/4);
    castT_all_kernel<<<dim3(16,16,4), 256, 0, stream>>>(Wq, Wk, Wv, Wd, wt);
    idx_kernel<<<4, 64, 0, stream>>>(mmask, rowidx);
    relb2_kernel<<<2048, 256, 0, stream>>>(rel, mmask, amask, rowidx, relb);
    // fused QKV gemm: N=3072 over concatenated W^T; V written transposed (last use of xb)
    gemm_bt<0><<<1536, 256, 0, stream>>>(xb, wt, bq, bk, bv, qb, kb2, vtb);
    attn7_kernel<<<1024, 256, 0, stream>>>(qb, kb2, vtb, relb, rowidx, ctx);
    gemm_bt<1><<<512, 256, 0, stream>>>(ctx, wt + 3*(1u<<20), bd, nullptr, nullptr,
                                        og, nullptr, nullptr);
    ln_kernel<<<8192, 256, 0, stream>>>(og, hidden, lng, lnb, out);
}